// Round 18
// baseline (23.994 us; speedup 1.0000x reference)
//
#include <hip/hip_runtime.h>
#include <math.h>

// Chamfer loss, B=8, C=3, M=N=4096, fp32 — MFMA, round 18.
//
// sq[m][n] = s2[m] + d2[n] - 2 s.d as a K=16 bf16 GEMM with hi/lo split:
//   query vec  = [-2xh,-2xh,-2xl,-2xl | y.. | z.. | s2h,s2l,1,1]
//   ref vec    = [ xh,  xl,  xh,  xl  | y.. | z.. | 1,1,d2h,d2l]
//
// Round-18 = round-17 (swapped MFMA: lane = query row, regs = 16 ref cols,
// epilogue = 1 shfl) + dual query fragments: wave owns 64 query rows
// (qfrag0/qfrag1), each ref ds_read_b128 feeds TWO MFMAs -> per-pair LDS
// reads halved (12.3K -> 6.1K cyc/CU). r13 proved read-halving is
// structurally safe; r13 was only neutral because it doubled the butterfly
// — r17's epilogue is ~free, so the gain should now be visible.
// KEEP: XOR swizzle c^((c>>3)&7) (write+read conflict-free; reads stay
// per-lane-constant at 64-col granularity), plain v_min chains (min3
// banned, r14: +8us), lb(256,4), grid 1024 (4 waves/SIMD), 32KB LDS
// single-chunk staging (2 barriers), 1MB partials, zero memsets.

constexpr int B = 8;
constexpr int M = 4096;   // == N

typedef __attribute__((ext_vector_type(8)))  short bf16x8;
typedef __attribute__((ext_vector_type(16))) float f32x16;

__device__ inline unsigned short bf16_of(float x) {   // round-to-nearest-even
    unsigned int u = __float_as_uint(x);
    u += 0x7FFFu + ((u >> 16) & 1u);
    return (unsigned short)(u >> 16);
}
__device__ inline float bf16_to_f(unsigned short h) {
    return __uint_as_float(((unsigned int)h) << 16);
}

// balanced min tree over 16 regs (no v_min3 fusion site)
__device__ inline float tree_min16(const f32x16 a) {
    const float t0 = fminf(a[0],  a[1]);
    const float t1 = fminf(a[2],  a[3]);
    const float t2 = fminf(a[4],  a[5]);
    const float t3 = fminf(a[6],  a[7]);
    const float t4 = fminf(a[8],  a[9]);
    const float t5 = fminf(a[10], a[11]);
    const float t6 = fminf(a[12], a[13]);
    const float t7 = fminf(a[14], a[15]);
    const float u0 = fminf(t0, t1);
    const float u1 = fminf(t2, t3);
    const float u2 = fminf(t4, t5);
    const float u3 = fminf(t6, t7);
    return fminf(fminf(u0, u1), fminf(u2, u3));
}

__device__ inline bf16x8 make_qfrag(const float* qb, int row, int hf) {
    const float x = qb[0 * M + row];
    const float y = qb[1 * M + row];
    const float z = qb[2 * M + row];
    const float s2 = x * x + y * y + z * z;
    const float xhf = bf16_to_f(bf16_of(x));
    const float yhf = bf16_to_f(bf16_of(y));
    const float zhf = bf16_to_f(bf16_of(z));
    // -2*hi exact (pow2 scale of a bf16 value)
    const unsigned short nxh = bf16_of(-2.0f * xhf), nxl = bf16_of(-2.0f * (x - xhf));
    const unsigned short nyh = bf16_of(-2.0f * yhf), nyl = bf16_of(-2.0f * (y - yhf));
    const unsigned short nzh = bf16_of(-2.0f * zhf), nzl = bf16_of(-2.0f * (z - zhf));
    const unsigned short s2h = bf16_of(s2);
    const unsigned short s2l = bf16_of(s2 - bf16_to_f(s2h));
    const unsigned short one = 0x3F80;
    bf16x8 alo, ahi;
    alo[0]=(short)nxh; alo[1]=(short)nxh; alo[2]=(short)nxl; alo[3]=(short)nxl;
    alo[4]=(short)nyh; alo[5]=(short)nyh; alo[6]=(short)nyl; alo[7]=(short)nyl;
    ahi[0]=(short)nzh; ahi[1]=(short)nzh; ahi[2]=(short)nzl; ahi[3]=(short)nzl;
    ahi[4]=(short)s2h; ahi[5]=(short)s2l; ahi[6]=(short)one; ahi[7]=(short)one;
    return hf ? ahi : alo;
}

// ws: part [4 cs][16 db][M] f32 @ 0   (1 MB) ; bsums [256] f32 @ 1 MB

// grid 1024 = (dir<<9 | b<<6 | rg<<2 | cs); 256 thr = 4 waves
// wave w: rows rg*256 + w*64 .. +64 ; cols cs*1024 .. +1024 (single chunk)
__global__ __launch_bounds__(256, 4) void chamfer_main(
    const float* __restrict__ src,
    const float* __restrict__ dst,
    float* __restrict__ part)
{
    int bid = blockIdx.x;
    const int cs  = bid & 3;  bid >>= 2;
    const int rg  = bid & 15; bid >>= 4;
    const int b   = bid & 7;  bid >>= 3;
    const int dir = bid;      // 0: rows=src scan dst ; 1: rows=dst scan src

    const float* __restrict__ qry = dir ? dst : src;   // query side (rows)
    const float* __restrict__ ref = dir ? src : dst;   // reference side (cols)

    const int tid  = threadIdx.x;
    const int wave = tid >> 6;
    const int l31  = tid & 31;
    const int hf   = (tid >> 5) & 1;    // k-group within wave

    __shared__ __align__(16) unsigned short bstage[2][1024][8];  // 32 KB

    // per-lane swizzled read rows: col i*64+l31 -> i*64 + sA ; +32 -> i*64 + sB
    const int sA = l31 ^ (l31 >> 3);
    const int sB = 32 + (l31 ^ (4 | (l31 >> 3)));

    // ---- two query fragments (B-operand; lane l31 = query row within group) ----
    const int rbase = rg * 256 + wave * 64;
    const float* qb = qry + (size_t)b * 3 * M;
    const bf16x8 qf0 = make_qfrag(qb, rbase + l31,      hf);
    const bf16x8 qf1 = make_qfrag(qb, rbase + 32 + l31, hf);

    float fwdE0 = 3.0e38f, fwdO0 = 3.0e38f;   // row-group 0, E/O tile chains
    float fwdE1 = 3.0e38f, fwdO1 = 3.0e38f;   // row-group 1

    const f32x16 zero = {};
    const float* rb = ref + (size_t)b * 3 * M + cs * 1024;

    // ---- stage all 1024 ref cols once (2 barriers total) ----
    {
        const int c0 = tid * 4;
        const float4 vx = *reinterpret_cast<const float4*>(&rb[0 * M + c0]);
        const float4 vy = *reinterpret_cast<const float4*>(&rb[1 * M + c0]);
        const float4 vz = *reinterpret_cast<const float4*>(&rb[2 * M + c0]);
        const float xs[4] = {vx.x, vx.y, vx.z, vx.w};
        const float ys[4] = {vy.x, vy.y, vy.z, vy.w};
        const float zs[4] = {vz.x, vz.y, vz.z, vz.w};
#pragma unroll
        for (int k = 0; k < 4; ++k) {
            const float x = xs[k], y = ys[k], z = zs[k];
            const float d2 = x * x + y * y + z * z;
            const unsigned short xh = bf16_of(x), xl = bf16_of(x - bf16_to_f(xh));
            const unsigned short yh = bf16_of(y), yl = bf16_of(y - bf16_to_f(yh));
            const unsigned short zh = bf16_of(z), zl = bf16_of(z - bf16_to_f(zh));
            const unsigned short d2h = bf16_of(d2);
            const unsigned short d2l = bf16_of(d2 - bf16_to_f(d2h));
            const unsigned short one = 0x3F80;
            bf16x8 v0, v1;
            v0[0]=(short)xh; v0[1]=(short)xl; v0[2]=(short)xh; v0[3]=(short)xl;
            v0[4]=(short)yh; v0[5]=(short)yl; v0[6]=(short)yh; v0[7]=(short)yl;
            v1[0]=(short)zh; v1[1]=(short)zl; v1[2]=(short)zh; v1[3]=(short)zl;
            v1[4]=(short)one; v1[5]=(short)one; v1[6]=(short)d2h; v1[7]=(short)d2l;
            const int c = c0 + k;
            const int swz = c ^ ((c >> 3) & 7);   // bijective, both-side min
            *reinterpret_cast<bf16x8*>(&bstage[0][swz][0]) = v0;
            *reinterpret_cast<bf16x8*>(&bstage[1][swz][0]) = v1;
        }
    }
    __syncthreads();

    // 32 col-tiles, 2 per step: 2 ds_read_b128 -> 4 SWAPPED MFMA (2 row-groups)
    // accs consumed eagerly by tree_min16 (1-2 live at a time)
#pragma unroll 4
    for (int i = 0; i < 16; ++i) {
        const bf16x8 bf0 = *reinterpret_cast<const bf16x8*>(&bstage[hf][i * 64 + sA][0]);
        const bf16x8 bf1 = *reinterpret_cast<const bf16x8*>(&bstage[hf][i * 64 + sB][0]);
        const f32x16 a00 = __builtin_amdgcn_mfma_f32_32x32x16_bf16(bf0, qf0, zero, 0, 0, 0);
        fwdE0 = fminf(fwdE0, tree_min16(a00));
        const f32x16 a01 = __builtin_amdgcn_mfma_f32_32x32x16_bf16(bf0, qf1, zero, 0, 0, 0);
        fwdE1 = fminf(fwdE1, tree_min16(a01));
        const f32x16 a10 = __builtin_amdgcn_mfma_f32_32x32x16_bf16(bf1, qf0, zero, 0, 0, 0);
        fwdO0 = fminf(fwdO0, tree_min16(a10));
        const f32x16 a11 = __builtin_amdgcn_mfma_f32_32x32x16_bf16(bf1, qf1, zero, 0, 0, 0);
        fwdO1 = fminf(fwdO1, tree_min16(a11));
    }

    // combine E/O + the two k-half lanes (lane l and l+32 hold same query row)
    float v0 = fminf(fwdE0, fwdO0);
    float v1 = fminf(fwdE1, fwdO1);
    v0 = fminf(v0, __shfl_xor(v0, 32));
    v1 = fminf(v1, __shfl_xor(v1, 32));
    if (hf == 0) {    // lanes 0..31 of each wave: coalesced 32-row segments
        float* pf = part + ((size_t)cs * 16 + dir * 8 + b) * M + rbase;
        pf[l31]      = v0;
        pf[32 + l31] = v1;
    }
}

// 256 blocks x 256 threads: min over the 4 col-splits, sqrt, block-sum -> bsums
__global__ __launch_bounds__(256) void chamfer_reduce(
    const float* __restrict__ part, float* __restrict__ bsums)
{
    const int idx = blockIdx.x * 256 + threadIdx.x;   // [0, 2*B*M)
    const int row = idx & (M - 1);
    const int db  = idx >> 12;                        // dir*8 + b

    const float* p = part + (size_t)db * M + row;
    const float v = fminf(fminf(p[0],              p[(size_t)16 * M]),
                          fminf(p[(size_t)32 * M], p[(size_t)48 * M]));

    float s = sqrtf(fmaxf(v, 0.0f));
#pragma unroll
    for (int off = 32; off > 0; off >>= 1) s += __shfl_down(s, off);
    __shared__ float partial[4];
    if ((threadIdx.x & 63) == 0) partial[threadIdx.x >> 6] = s;
    __syncthreads();
    if (threadIdx.x == 0)
        bsums[blockIdx.x] = partial[0] + partial[1] + partial[2] + partial[3];
}

// 1 block: total, scale, plain-store out[0..2] (no memset needed anywhere)
__global__ __launch_bounds__(256) void chamfer_final(
    const float* __restrict__ bsums, float* __restrict__ out)
{
    float s = bsums[threadIdx.x];
#pragma unroll
    for (int off = 32; off > 0; off >>= 1) s += __shfl_down(s, off);
    __shared__ float partial[4];
    if ((threadIdx.x & 63) == 0) partial[threadIdx.x >> 6] = s;
    __syncthreads();
    if (threadIdx.x == 0) {
        const float tot = (partial[0] + partial[1] + partial[2] + partial[3])
                        * (1.0f / (float)(B * M));   // fwd /(B*M), bwd /(B*N), M==N
        out[0] = tot;
        out[1] = tot;
        out[2] = tot;
    }
}

extern "C" void kernel_launch(void* const* d_in, const int* in_sizes, int n_in,
                              void* d_out, int out_size, void* d_ws, size_t ws_size,
                              hipStream_t stream)
{
    const float* src = (const float*)d_in[0];   // [B,3,M]
    const float* dst = (const float*)d_in[1];   // [B,3,N]
    float* out = (float*)d_out;                 // 3 floats

    float* part  = (float*)d_ws;                          // 1 MB, fully written
    float* bsums = (float*)((char*)d_ws + (1u << 20));    // 256 floats, fully written

    chamfer_main  <<<1024, 256, 0, stream>>>(src, dst, part);
    chamfer_reduce<<<256, 256, 0, stream>>>(part, bsums);
    chamfer_final <<<1, 256, 0, stream>>>(bsums, out);
}